// Round 9
// baseline (432.595 us; speedup 1.0000x reference)
//
#include <hip/hip_runtime.h>

// NCC loss: 1 - mean( cross^2 / (pvar*tvar + 1e-8) ) over 9^3 zero-padded
// box windows, input (4,1,160,160,160) fp32.
//
// R9: R8 disproved the grid-residency theory (2x blocks -> worse). Attack
// the intra-block critical path instead: R5's wave 0 was the convoy head
// (staging + ALL y+cc every step). Now TWO slices per barrier:
//   staging (all waves, 144 lanes): fold+DPP-x-pass slice A then B into two
//   s2 buffers -> ONE barrier -> wave1 does y+cc for slice A, wave2 for
//   slice B (identical proven 12-tap code), wave0 stages only.
// Max per-wave work per 2 slices: 540 -> ~400 instr-equiv; barriers 40->20.
// Ring slot pairs stay compile-time (9-periodic over double-steps).
// Locked-in: __launch_bounds__(192,3) ONLY (R6/R7: any min-waves >=4 forces
// a catastrophic VGPR spill; needs ~76-140 regs, cap at (192,3) is 170).
// ZCHUNK=40, 1600 blocks (R8: 3200 was worse). s2 stride-20 (0 conflicts).

#define DSZ    160
#define NBATCH 4
#define RAD    4
#define TX     16
#define TY     16
#define ZCHUNK 40
#define SLICE  (DSZ*DSZ)
#define VOL    (DSZ*DSZ*DSZ)
#define WINV   (1.0f/729.0f)
#define NVOX_INV (1.0f/16384000.0f)

#define NROW 24        // halo rows per tile
#define NGRP 6         // x groups of 4 halo cols (24)
#define BLK  192

#define S2_RS 20                 // row stride: 16 outputs + pad (2-way banks)
#define S2_FS (NROW*S2_RS)       // 480 floats per field
#define S2_BUF (5*S2_FS)         // 2400 floats per slice-buffer (== 0 mod 32)

__device__ __forceinline__ float dpp_shl1(float x) {  // lane i <- lane i+1 (16-lane row, OOB=0)
    return __int_as_float(__builtin_amdgcn_update_dpp(0, __float_as_int(x), 0x101, 0xf, 0xf, true));
}
__device__ __forceinline__ float dpp_shl2(float x) {  // lane i <- lane i+2
    return __int_as_float(__builtin_amdgcn_update_dpp(0, __float_as_int(x), 0x102, 0xf, 0xf, true));
}

__global__ __launch_bounds__(BLK, 3)
void ncc_main(const float* __restrict__ pred, const float* __restrict__ tgt,
              float* __restrict__ accum)
{
    const int tid = threadIdx.x;
    const int row = tid >> 3;      // 0..23 halo row (staging)
    const int g   = tid & 7;       // 0..7; g<6 = active x-group
    const int ox  = blockIdx.x * TX;
    const int oy  = blockIdx.y * TY;
    const int batch = blockIdx.z >> 2;
    const int z0  = (blockIdx.z & 3) * ZCHUNK;

    __shared__ __align__(16) float s2buf[4*S2_BUF];  // 38.4 KB: [parity][slice]
    __shared__ float red[2];

    const bool stg = (g < NGRP);
    const int  gy  = oy - RAD + row;
    const int  gx0 = ox - RAD + g*4;
    const bool ldok = stg && (gy >= 0) && (gy < DSZ) && (gx0 >= 0) && (gx0 + 3 < DSZ);
    const int  base = batch*VOL + gy*DSZ + gx0;     // only used under ldok

    // register ring of raw slice values (own 4 columns), chunk-local slots
    float rp[9][4], rt[9][4];
    float zs[5][4];
    #pragma unroll
    for (int k = 0; k < 9; ++k)
        #pragma unroll
        for (int j = 0; j < 4; ++j) { rp[k][j] = 0.f; rt[k][j] = 0.f; }
    #pragma unroll
    for (int f = 0; f < 5; ++f)
        #pragma unroll
        for (int j = 0; j < 4; ++j) zs[f][j] = 0.f;

    // ---- warm-up: issue ALL loads (slices z0-4..z0+3 -> slots 0..7), then
    // fold once. Independent loads -> single waitcnt drain.
    #pragma unroll
    for (int i = 0; i < 8; ++i) {
        int z = z0 - RAD + i;               // always < DSZ here
        if (ldok && z >= 0) {
            float4 p4 = *(const float4*)(pred + base + z*SLICE);
            float4 t4 = *(const float4*)(tgt  + base + z*SLICE);
            rp[i][0]=p4.x; rp[i][1]=p4.y; rp[i][2]=p4.z; rp[i][3]=p4.w;
            rt[i][0]=t4.x; rt[i][1]=t4.y; rt[i][2]=t4.z; rt[i][3]=t4.w;
        }
    }
    #pragma unroll
    for (int i = 0; i < 8; ++i)
        #pragma unroll
        for (int j = 0; j < 4; ++j) {
            float p = rp[i][j], t = rt[i][j];
            zs[0][j] += p;   zs[1][j] += t;
            zs[2][j] += p*p; zs[3][j] += t*t;
            zs[4][j] += p*t;
        }

    // ---- streaming prefetch: 2 slices ahead ----
    int za = z0 + RAD;                      // absolute z of next fetch
    int zmax = z0 + ZCHUNK + RAD;           // last useful slice + 1
    if (zmax > DSZ) zmax = DSZ;
    float4 paA={0,0,0,0}, taA={0,0,0,0}, paB={0,0,0,0}, taB={0,0,0,0};
    auto pf2 = [&]() {
        float4 a={0,0,0,0}, b={0,0,0,0}, c={0,0,0,0}, d={0,0,0,0};
        if (ldok) {
            if (za < zmax) {
                a = *(const float4*)(pred + base + za*SLICE);
                b = *(const float4*)(tgt  + base + za*SLICE);
            }
            if (za + 1 < zmax) {
                c = *(const float4*)(pred + base + (za+1)*SLICE);
                d = *(const float4*)(tgt  + base + (za+1)*SLICE);
            }
        }
        paA=a; taA=b; paB=c; taB=d; za += 2;
    };
    pf2();

    int pb = 1;          // parity toggle (first step -> 0)
    float acc = 0.f;

// fold one slice (slot SLOT) into zs + DPP x 9-sum -> DST slice-buffer
#define FOLD_X(SLOT, PC, TC, DST) do {                                        \
    _Pragma("unroll")                                                         \
    for (int j = 0; j < 4; ++j) {                                             \
        float ps = rp[SLOT][j], qs = rt[SLOT][j];                             \
        float d0 = PC[j] - ps, d1 = TC[j] - qs;                               \
        zs[0][j] += d0;                                                       \
        zs[1][j] += d1;                                                       \
        zs[2][j] += d0*(PC[j] + ps);                                          \
        zs[3][j] += d1*(TC[j] + qs);                                          \
        zs[4][j] += PC[j]*TC[j] - ps*qs;                                      \
        rp[SLOT][j] = PC[j];  rt[SLOT][j] = TC[j];                            \
    }                                                                         \
    _Pragma("unroll")                                                         \
    for (int f = 0; f < 5; ++f) {                                             \
        float P0 = zs[f][0];                                                  \
        float P1 = P0 + zs[f][1];                                             \
        float P2 = P1 + zs[f][2];                                             \
        float P3 = P2 + zs[f][3];                                             \
        float T  = dpp_shl1(P3);                                              \
        float Q0 = dpp_shl2(P0), Q1 = dpp_shl2(P1);                           \
        float Q2 = dpp_shl2(P2), Q3 = dpp_shl2(P3);                           \
        if (g < 4) {                                                          \
            float b = P3 + T;                                                 \
            float* dstp = &(DST)[f*S2_FS + row*S2_RS + g*4];                  \
            dstp[0] = b + Q0;                                                 \
            dstp[1] = b - P0 + Q1;                                            \
            dstp[2] = b - P1 + Q2;                                            \
            dstp[3] = b - P2 + Q3;                                            \
        }                                                                     \
    }                                                                         \
} while (0)

// double-step: outputs s=2d (slot SA) and s=2d+1 (slot SB)
#define NCC_STEP2(SA, SB) do {                                                \
    pb ^= 1;                                                                  \
    float* sA = &s2buf[(pb*2 + 0)*S2_BUF];                                    \
    float* sB = &s2buf[(pb*2 + 1)*S2_BUF];                                    \
    if (stg) {                                                                \
        float pcA[4]={paA.x,paA.y,paA.z,paA.w}, tcA[4]={taA.x,taA.y,taA.z,taA.w};\
        float pcB[4]={paB.x,paB.y,paB.z,paB.w}, tcB[4]={taB.x,taB.y,taB.z,taB.w};\
        pf2();   /* issue next 2 slices' loads; drain behind the barrier */   \
        FOLD_X(SA, pcA, tcA, sA);                                             \
        FOLD_X(SB, pcB, tcB, sB);                                             \
    }                                                                         \
    __syncthreads();                                                          \
    if (tid >= 64) {   /* wave1 -> slice A, wave2 -> slice B */               \
        const float* sbuf = (tid < 128) ? sA : sB;                            \
        const int u = tid & 63;                                               \
        const int x = u & 15, yq = (u >> 4)*4;                                \
        float S[5][4];                                                        \
        _Pragma("unroll")                                                     \
        for (int f = 0; f < 5; ++f) {                                         \
            const float* col = &sbuf[f*S2_FS + x];                            \
            float r0 = col[(yq+0)*S2_RS], r1 = col[(yq+1)*S2_RS];             \
            float r2 = col[(yq+2)*S2_RS], r3 = col[(yq+3)*S2_RS];             \
            float run = r0+r1+r2+r3 + col[(yq+4)*S2_RS] + col[(yq+5)*S2_RS]   \
                      + col[(yq+6)*S2_RS] + col[(yq+7)*S2_RS];                \
            run += col[(yq+8)*S2_RS];        S[f][0] = run;                   \
            run += col[(yq+9)*S2_RS]  - r0;  S[f][1] = run;                   \
            run += col[(yq+10)*S2_RS] - r1;  S[f][2] = run;                   \
            run += col[(yq+11)*S2_RS] - r2;  S[f][3] = run;                   \
        }                                                                     \
        _Pragma("unroll")                                                     \
        for (int i = 0; i < 4; ++i) {                                         \
            float Sp = S[0][i], St = S[1][i];                                 \
            float cross = S[4][i] - Sp*St*WINV;                               \
            float pv    = S[2][i] - Sp*Sp*WINV;                               \
            float tv    = S[3][i] - St*St*WINV;                               \
            acc += cross*cross / (pv*tv + 1e-8f);                             \
        }                                                                     \
    }                                                                         \
} while (0)

    // 20 double-steps cover s=0..39; slot pair for double-step d is
    // ((2d+8)%9, (2d+9)%9): prologue d=0,1 then 9-periodic from d=2.
    NCC_STEP2(8,0); NCC_STEP2(1,2);
    for (int it = 0; it < 2; ++it) {
        NCC_STEP2(3,4); NCC_STEP2(5,6); NCC_STEP2(7,8);
        NCC_STEP2(0,1); NCC_STEP2(2,3); NCC_STEP2(4,5);
        NCC_STEP2(6,7); NCC_STEP2(8,0); NCC_STEP2(1,2);
    }
#undef NCC_STEP2
#undef FOLD_X

    // cc partials live in waves 1 and 2
    if (tid >= 64) {
        float v = acc;
        #pragma unroll
        for (int off = 32; off > 0; off >>= 1) v += __shfl_down(v, off, 64);
        if ((tid & 63) == 0) red[(tid >> 6) - 1] = v;
    }
    __syncthreads();
    if (tid == 0) atomicAdd(accum, red[0] + red[1]);
}

__global__ void ncc_final(const float* __restrict__ accum, float* __restrict__ out)
{
    out[0] = 1.0f - accum[0] * NVOX_INV;
}

extern "C" void kernel_launch(void* const* d_in, const int* in_sizes, int n_in,
                              void* d_out, int out_size, void* d_ws, size_t ws_size,
                              hipStream_t stream)
{
    const float* pred = (const float*)d_in[0];
    const float* tgt  = (const float*)d_in[1];
    float* out = (float*)d_out;
    float* ws  = (float*)d_ws;

    hipMemsetAsync(ws, 0, sizeof(float), stream);
    dim3 grid(DSZ/TX, DSZ/TY, NBATCH*4);   // 10 x 10 x 16 = 1600 blocks
    ncc_main<<<grid, BLK, 0, stream>>>(pred, tgt, ws);
    ncc_final<<<1, 1, 0, stream>>>(ws, out);
}